// Round 8
// baseline (229.204 us; speedup 1.0000x reference)
//
#include <hip/hip_runtime.h>

// SpecialSpmmFinal: out[n1, f] = sum over edges e with src[e]==n1 of edge_w[e, f]
// N1=100000, E=3.2M, F=32.
//
// R7 pipeline (F==32)  [resubmit: R7 bench died to container failure]:
//   1. zero counts + ovf counter
//   2. hist_fill: fused histogram + padded-slot fill, XCD-range-partitioned
//      (range = blockIdx&7 -> counts slice 50KB + perm_pad slice 3.2MB stay in
//      that XCD's L2). 8 edges/thread (2x int4) to halve loop overhead.
//   3. gather_sum: same range mapping; 8 lanes/node; perm indices loaded
//      cooperatively (lane loads pp[i+sub], __shfl-broadcast) -> 9 VMEM issues
//      per 8 rows instead of 16. edge_w rows NT-loaded, out NT-stored.
//   4. overflow_scatter: degree > PAD correctness guard (no-op expected).

#define NR   8     // node ranges == XCDs
#define PAD  64    // padded slots per node (mean degree 32, max ~59)
#define OVF_CAP 8192
#define GPB  32    // nodes per gather block (256 thr / 8 lanes-per-node)

typedef float f32x4 __attribute__((ext_vector_type(4)));

__global__ __launch_bounds__(256) void zero_kernel(int* __restrict__ p, int n) {
    int i = blockIdx.x * 256 + threadIdx.x;
    if (i < n) p[i] = 0;
}

// Fused histogram + padded fill, node-range partitioned, 8 edges/thread.
__global__ __launch_bounds__(256) void hist_fill_kernel(const int* __restrict__ src,
                                                        int* __restrict__ counts,
                                                        int* __restrict__ perm_pad,
                                                        int* __restrict__ ovf,
                                                        int E, int N1, int rsize) {
    int range = blockIdx.x & (NR - 1);       // consecutive blocks -> different XCDs
    int lo = range * rsize;
    int hi = lo + rsize; if (hi > N1) hi = N1;
    int bid = blockIdx.x >> 3;
    int nblk = gridDim.x >> 3;
    int stride = nblk * 256 * 8;
    int e0 = (bid * 256 + threadIdx.x) * 8;
    for (; e0 + 8 <= E; e0 += stride) {
        int4 sa = *reinterpret_cast<const int4*>(src + e0);
        int4 sb = *reinterpret_cast<const int4*>(src + e0 + 4);
        int ss[8] = {sa.x, sa.y, sa.z, sa.w, sb.x, sb.y, sb.z, sb.w};
        #pragma unroll
        for (int k = 0; k < 8; ++k) {
            int s = ss[k];
            if (s >= lo && s < hi) {
                int r = atomicAdd(&counts[s], 1);
                if (__builtin_expect(r < PAD, 1)) perm_pad[s * PAD + r] = e0 + k;
                else {
                    int p = atomicAdd(&ovf[0], 1);
                    if (p < OVF_CAP) ovf[1 + p] = e0 + k;
                }
            }
        }
    }
    // tail (E % 8 != 0): only the threads whose window straddles E
    for (int e = e0; e < E; ++e) {
        int s = src[e];
        if (s >= lo && s < hi) {
            int r = atomicAdd(&counts[s], 1);
            if (r < PAD) perm_pad[s * PAD + r] = e;
            else {
                int p = atomicAdd(&ovf[0], 1);
                if (p < OVF_CAP) ovf[1 + p] = e;
            }
        }
    }
}

// gather-sum (F == 32): 8 lanes per node, lane owns one f32x4 quad of the row.
// Cooperative perm loads: lane loads pp[i+sub]; indices distributed via __shfl.
__global__ __launch_bounds__(256) void gather_sum_kernel(const int* __restrict__ counts,
                                                         const int* __restrict__ perm_pad,
                                                         const f32x4* __restrict__ w4,
                                                         f32x4* __restrict__ out4,
                                                         int N1, int rsize) {
    int range = blockIdx.x & (NR - 1);       // same XCD as hist_fill's writes
    int bir   = blockIdx.x >> 3;             // block index within range
    int node  = range * rsize + bir * GPB + (threadIdx.x >> 3);
    int hi    = range * rsize + rsize; if (hi > N1) hi = N1;
    if (node >= hi) return;
    int sub  = threadIdx.x & 7;
    int gbase = (threadIdx.x & 63) & 0x38;   // wave-relative base lane of this 8-lane group
    int cnt = counts[node]; if (cnt > PAD) cnt = PAD;
    const int* pp = perm_pad + node * PAD;
    f32x4 acc = {0.f, 0.f, 0.f, 0.f};
    int i = 0;
    for (; i + 8 <= cnt; i += 8) {
        int myidx = pp[i + sub];             // one coalesced 32B read per group
        int e0 = __shfl(myidx, gbase | 0, 64);
        int e1 = __shfl(myidx, gbase | 1, 64);
        int e2 = __shfl(myidx, gbase | 2, 64);
        int e3 = __shfl(myidx, gbase | 3, 64);
        int e4 = __shfl(myidx, gbase | 4, 64);
        int e5 = __shfl(myidx, gbase | 5, 64);
        int e6 = __shfl(myidx, gbase | 6, 64);
        int e7 = __shfl(myidx, gbase | 7, 64);
        f32x4 a0 = __builtin_nontemporal_load(&w4[(long long)e0 * 8 + sub]);
        f32x4 a1 = __builtin_nontemporal_load(&w4[(long long)e1 * 8 + sub]);
        f32x4 a2 = __builtin_nontemporal_load(&w4[(long long)e2 * 8 + sub]);
        f32x4 a3 = __builtin_nontemporal_load(&w4[(long long)e3 * 8 + sub]);
        f32x4 a4 = __builtin_nontemporal_load(&w4[(long long)e4 * 8 + sub]);
        f32x4 a5 = __builtin_nontemporal_load(&w4[(long long)e5 * 8 + sub]);
        f32x4 a6 = __builtin_nontemporal_load(&w4[(long long)e6 * 8 + sub]);
        f32x4 a7 = __builtin_nontemporal_load(&w4[(long long)e7 * 8 + sub]);
        acc += ((a0 + a1) + (a2 + a3)) + ((a4 + a5) + (a6 + a7));
    }
    for (; i < cnt; ++i) {                   // tail: broadcast load per edge
        f32x4 a = __builtin_nontemporal_load(&w4[(long long)pp[i] * 8 + sub]);
        acc += a;
    }
    __builtin_nontemporal_store(acc, &out4[(long long)node * 8 + sub]);
}

// Correctness guard: contributions of overflow edges (degree > PAD).
__global__ __launch_bounds__(256) void overflow_scatter_kernel(const int* __restrict__ src,
                                                               const float* __restrict__ w,
                                                               const int* __restrict__ ovf,
                                                               float* __restrict__ out) {
    int n = ovf[0]; if (n > OVF_CAP) n = OVF_CAP;
    long long total = (long long)n * 32;
    int stride = gridDim.x * 256;
    for (long long t = blockIdx.x * 256 + threadIdx.x; t < total; t += stride) {
        int e = ovf[1 + (int)(t >> 5)];
        int f = (int)(t & 31);
        unsafeAtomicAdd(out + (long long)src[e] * 32 + f, w[(long long)e * 32 + f]);
    }
}

// ---- fallback: direct atomic scatter (F != 32 or tiny ws) ----
__global__ __launch_bounds__(256) void zero_out_kernel(float* __restrict__ out, int n) {
    int i = blockIdx.x * 256 + threadIdx.x;
    if (i < n) out[i] = 0.0f;
}

__global__ __launch_bounds__(256) void scatter_add_generic_kernel(
    const int* __restrict__ src, const float* __restrict__ w,
    float* __restrict__ out, long long total, int F) {
    long long tid = (long long)blockIdx.x * 256 + threadIdx.x;
    if (tid >= total) return;
    int e = (int)(tid / F);
    int f = (int)(tid % F);
    unsafeAtomicAdd(out + (long long)src[e] * F + f, w[tid]);
}

extern "C" void kernel_launch(void* const* d_in, const int* in_sizes, int n_in,
                              void* d_out, int out_size, void* d_ws, size_t ws_size,
                              hipStream_t stream) {
    const int* edge = (const int*)d_in[0];    // [2, E]; first E = src
    const float* w  = (const float*)d_in[1];  // [E, F]
    float* out      = (float*)d_out;          // [N1, F]

    const int E  = in_sizes[0] / 2;
    const int F  = in_sizes[1] / E;
    const int N1 = out_size / F;
    const int* src = edge;
    const int rsize = (N1 + NR - 1) / NR;

    // ws layout: counts[N1] | ovf[1+OVF_CAP] | perm_pad[N1*PAD]
    size_t need = ((size_t)N1 + 1 + OVF_CAP + (size_t)N1 * PAD) * sizeof(int);

    if (F == 32 && ws_size >= need) {
        int* counts   = (int*)d_ws;
        int* ovf      = counts + N1;
        int* perm_pad = ovf + 1 + OVF_CAP;

        zero_kernel<<<(N1 + 1 + 255) / 256, 256, 0, stream>>>(counts, N1 + 1);
        hist_fill_kernel<<<NR * 256, 256, 0, stream>>>(src, counts, perm_pad, ovf, E, N1, rsize);
        int nbpr = (rsize + GPB - 1) / GPB;                 // gather blocks per range
        gather_sum_kernel<<<NR * nbpr, 256, 0, stream>>>(
            counts, perm_pad, (const f32x4*)w, (f32x4*)out, N1, rsize);
        overflow_scatter_kernel<<<64, 256, 0, stream>>>(src, w, ovf, out);
    } else {
        zero_out_kernel<<<(out_size + 255) / 256, 256, 0, stream>>>(out, out_size);
        long long total = (long long)E * F;
        scatter_add_generic_kernel<<<(int)((total + 255) / 256), 256, 0, stream>>>(
            src, w, out, total, F);
    }
}